// Round 8
// baseline (238.655 us; speedup 1.0000x reference)
//
#include <hip/hip_runtime.h>
#include <hip/hip_bf16.h>
#include <math.h>

#define NN 1024

typedef short bf16x8 __attribute__((ext_vector_type(8)));
typedef float f32x4 __attribute__((ext_vector_type(4)));

__device__ __forceinline__ unsigned rne_u(float x) {
    unsigned u = __float_as_uint(x);
    return u + 0x7fffu + ((u >> 16) & 1u);
}
__device__ __forceinline__ float bf16_up_bits(unsigned hi16) {
    return __uint_as_float(hi16 << 16);
}
__device__ __forceinline__ unsigned pair_pack(float a, float b) {   // a->low, b->high, RNE
    return (rne_u(a) >> 16) | (rne_u(b) & 0xffff0000u);
}
// packed fp32x2 -> bf16x2 (v_cvt_pk_bf16_f32 on gfx950)
__device__ __forceinline__ unsigned pack2(float a, float b) {
    __hip_bfloat162 h = __float22bfloat162_rn(make_float2(a, b));
    unsigned u;
    __builtin_memcpy(&u, &h, 4);
    return u;
}

union U16 { uint4 u; bf16x8 v; };
union P4 { unsigned w[4]; bf16x8 v; };

// h1 fragment: relu(x + c) -> bf16 RNE, element e at k = q*8+e
__device__ __forceinline__ bf16x8 mk_frag(float4 x0, float4 x1, float4 c0, float4 c1) {
    P4 u;
    u.w[0] = pack2(fmaxf(x0.x + c0.x, 0.f), fmaxf(x0.y + c0.y, 0.f));
    u.w[1] = pack2(fmaxf(x0.z + c0.z, 0.f), fmaxf(x0.w + c0.w, 0.f));
    u.w[2] = pack2(fmaxf(x1.x + c1.x, 0.f), fmaxf(x1.y + c1.y, 0.f));
    u.w[3] = pack2(fmaxf(x1.z + c1.z, 0.f), fmaxf(x1.w + c1.w, 0.f));
    return u.v;
}

// ---- prep: blocks [0,512): A' = z_c@W1c + b1 scattered into FRAG-ORDER layout
//            Apf[tile=j>>4][lane][slot]; B = z_d@W1d row-major.
//            blocks [512,514): W2 -> MFMA frag layout (hi+lo bf16), zero Srow.
__global__ void prep_kernel(const float* __restrict__ z_c, const float* __restrict__ z_d,
                            const float* __restrict__ W1, const float* __restrict__ b1,
                            const float* __restrict__ W2,
                            float* __restrict__ Apf, float* __restrict__ Bp,
                            uint4* __restrict__ W2hi, uint4* __restrict__ W2lo,
                            float* __restrict__ Srow) {
    if (blockIdx.x < 512) {
        int t = blockIdx.x * 256 + threadIdx.x;
        int sel = t >> 16;            // 0 -> A' (frag-order), 1 -> B (row-major)
        int idx = t & 0xffff;
        int n = idx >> 6, h = idx & 63;
        const float* z = (sel ? z_d : z_c) + n * 64;
        const float* w = W1 + (sel ? 4096 : 0) + h;   // W1 (128,64) row-major
        float a0 = sel ? 0.f : b1[h], a1 = 0.f;
        #pragma unroll
        for (int k = 0; k < 64; k += 2) {
            a0 = fmaf(z[k],     w[k * 64],       a0);
            a1 = fmaf(z[k + 1], w[(k + 1) * 64], a1);
        }
        float val = a0 + a1;
        if (sel) {
            Bp[idx] = val;
        } else {
            // frag-order scatter: tile = n>>4; lane = q*16 + (n&15); slot = s*8 + e
            int s = h >> 5, kk = h & 31, q = kk >> 3, e = kk & 7;
            int lane = q * 16 + (n & 15);
            Apf[(n >> 4) * 1024 + lane * 16 + s * 8 + e] = val;
        }
    } else {
        int tt = (blockIdx.x - 512) * 256 + threadIdx.x;   // 0..511
        Srow[tt] = 0.f; Srow[tt + 512] = 0.f;
        int f = tt >> 6, lane = tt & 63;                   // f = s*4 + t
        int s = f >> 2, t4 = f & 3, q = lane >> 4, l15 = lane & 15;
        int n = t4 * 16 + l15;
        unsigned hi[4], lo[4];
        #pragma unroll
        for (int p = 0; p < 4; ++p) {
            int k = s * 32 + q * 8 + 2 * p;
            float w0 = W2[k * 64 + n], w1 = W2[(k + 1) * 64 + n];
            unsigned h0 = rne_u(w0) >> 16, h1 = rne_u(w1) >> 16;
            hi[p] = h0 | (h1 << 16);
            lo[p] = pair_pack(w0 - bf16_up_bits(h0), w1 - bf16_up_bits(h1));
        }
        W2hi[f * 64 + lane] = make_uint4(hi[0], hi[1], hi[2], hi[3]);
        W2lo[f * 64 + lane] = make_uint4(lo[0], lo[1], lo[2], lo[3]);
    }
}

// ---- main: block = (i, quarter). 4096 blocks x 256 thr; each wave 4 j-tiles of 16.
// R7 register-diet structure (two h-half passes, 52 VGPR) unchanged; the ONLY change
// vs R7 is __launch_bounds__(256, 8): R7's (256,4) capped residency at 4 waves/SIMD
// and occupancy measured 32% (~10/32 waves) -> the cap itself was binding. 52 VGPR
// fits the 64-reg budget that 8 waves/SIMD requires.
__global__ void __launch_bounds__(256, 8)
main_kernel(const float* __restrict__ Apf, const float* __restrict__ Bp,
            const uint4* __restrict__ W2hi, const uint4* __restrict__ W2lo,
            const float* __restrict__ b2, const float* __restrict__ Wo,
            float* __restrict__ Srow, float* __restrict__ T0row) {
    const int i       = blockIdx.x >> 2;
    const int quarter = blockIdx.x & 3;
    const int lane = threadIdx.x & 63;
    const int wave = threadIdx.x >> 6;
    const int l15  = lane & 15;
    const int q    = lane >> 4;

    const int tbase = quarter * 16 + wave * 4;
    const float* apf = Apf + tbase * 1024 + lane * 16;

    // B_i per-lane slice, k = s*32 + q*8 + e  (dead after frag build)
    const float* bpr = Bp + i * 64 + q * 8;
    float4 c00 = *(const float4*)(bpr);
    float4 c01 = *(const float4*)(bpr + 4);
    float4 c10 = *(const float4*)(bpr + 32);
    float4 c11 = *(const float4*)(bpr + 36);

    // Build A-frags for all 4 tiles upfront (frag-order loads: lane-contig 64 B)
    bf16x8 A0[4], A1[4];
    #pragma unroll
    for (int tile = 0; tile < 4; ++tile) {
        const float4* p = (const float4*)(apf + tile * 1024);
        float4 x0 = p[0], x1 = p[1], x2 = p[2], x3 = p[3];
        A0[tile] = mk_frag(x0, x1, c00, c01);   // k 0..31
        A1[tile] = mk_frag(x2, x3, c10, c11);   // k 32..63
    }

    float psum[4] = {0.f, 0.f, 0.f, 0.f};

    // Two passes over h-halves; W2 frags for one half only (32 regs) live at a time.
    for (int th = 0; th < 2; ++th) {
        bf16x8 whi[2][2], wlo[2][2];   // [s][t-within-half]
        #pragma unroll
        for (int s = 0; s < 2; ++s)
            #pragma unroll
            for (int t = 0; t < 2; ++t) {
                int f = s * 4 + th * 2 + t;
                U16 a, b;
                a.u = W2hi[f * 64 + lane];
                b.u = W2lo[f * 64 + lane];
                whi[s][t] = a.v; wlo[s][t] = b.v;
            }
        f32x4 b2v[2];
        float wov[2][4];
        #pragma unroll
        for (int t = 0; t < 2; ++t) {
            float4 bt = *(const float4*)(b2 + th * 32 + t * 16 + q * 4);
            float4 wt = *(const float4*)(Wo + th * 32 + t * 16 + q * 4);
            b2v[t] = (f32x4){bt.x, bt.y, bt.z, bt.w};
            wov[t][0] = wt.x; wov[t][1] = wt.y; wov[t][2] = wt.z; wov[t][3] = wt.w;
        }

        #pragma unroll
        for (int tile = 0; tile < 4; ++tile) {
            f32x4 acc0 = b2v[0], acc1 = b2v[1];   // b2 folded into init
            acc0 = __builtin_amdgcn_mfma_f32_16x16x32_bf16(whi[0][0], A0[tile], acc0, 0, 0, 0);
            acc1 = __builtin_amdgcn_mfma_f32_16x16x32_bf16(whi[0][1], A0[tile], acc1, 0, 0, 0);
            acc0 = __builtin_amdgcn_mfma_f32_16x16x32_bf16(whi[1][0], A1[tile], acc0, 0, 0, 0);
            acc1 = __builtin_amdgcn_mfma_f32_16x16x32_bf16(whi[1][1], A1[tile], acc1, 0, 0, 0);
            acc0 = __builtin_amdgcn_mfma_f32_16x16x32_bf16(wlo[0][0], A0[tile], acc0, 0, 0, 0);
            acc1 = __builtin_amdgcn_mfma_f32_16x16x32_bf16(wlo[0][1], A0[tile], acc1, 0, 0, 0);
            acc0 = __builtin_amdgcn_mfma_f32_16x16x32_bf16(wlo[1][0], A1[tile], acc0, 0, 0, 0);
            acc1 = __builtin_amdgcn_mfma_f32_16x16x32_bf16(wlo[1][1], A1[tile], acc1, 0, 0, 0);

            // partial T1 over this h-half: per lane h = (th*2 + t)*16 + q*4 + r
            float p0 = 0.f, p1 = 0.f, p2 = 0.f, p3 = 0.f;
            p0 = fmaf(fmaxf(acc0[0], 0.f), wov[0][0], p0);
            p1 = fmaf(fmaxf(acc0[1], 0.f), wov[0][1], p1);
            p2 = fmaf(fmaxf(acc0[2], 0.f), wov[0][2], p2);
            p3 = fmaf(fmaxf(acc0[3], 0.f), wov[0][3], p3);
            p0 = fmaf(fmaxf(acc1[0], 0.f), wov[1][0], p0);
            p1 = fmaf(fmaxf(acc1[1], 0.f), wov[1][1], p1);
            p2 = fmaf(fmaxf(acc1[2], 0.f), wov[1][2], p2);
            p3 = fmaf(fmaxf(acc1[3], 0.f), wov[1][3], p3);
            psum[tile] += (p0 + p1) + (p2 + p3);
        }
    }

    // Epilogue: 4 independent reduce/exp chains
    float sacc = 0.f;
    #pragma unroll
    for (int tile = 0; tile < 4; ++tile) {
        float ps = psum[tile];
        ps += __shfl_xor(ps, 16);
        ps += __shfl_xor(ps, 32);   // T1[j], replicated over the 4 q-groups
        const int j = (tbase + tile) * 16 + l15;
        if (j == i && q == 0) T0row[i] = ps;   // diagonal: exactly one writer
        sacc += __expf(ps);
    }
    // reduce over l15 only (q-groups are exact replicas -> exact sum)
    sacc += __shfl_xor(sacc, 1);
    sacc += __shfl_xor(sacc, 2);
    sacc += __shfl_xor(sacc, 4);
    sacc += __shfl_xor(sacc, 8);
    if (lane == 0) atomicAdd(&Srow[i], sacc);   // 16 adds per i, 1024 addresses
}

// ---- combine+finish: 1 block x 1024 thr. bound = mean(T0) - (mean(log Srow) - ln N)
__global__ void __launch_bounds__(1024)
combine_finish(const float* __restrict__ Srow, const float* __restrict__ T0row,
               float* __restrict__ out) {
    int i = threadIdx.x;
    float l  = logf(Srow[i]);
    float t0 = T0row[i];
    #pragma unroll
    for (int off = 1; off < 64; off <<= 1) {
        l  += __shfl_xor(l, off);
        t0 += __shfl_xor(t0, off);
    }
    __shared__ float sl[16], st[16];
    int w = threadIdx.x >> 6;
    if ((threadIdx.x & 63) == 0) { sl[w] = l; st[w] = t0; }
    __syncthreads();
    if (threadIdx.x == 0) {
        float L = 0.f, T = 0.f;
        #pragma unroll
        for (int k = 0; k < 16; ++k) { L += sl[k]; T += st[k]; }
        out[0] = (T - L) * (1.0f / 1024.0f) + 6.9314718055994531f;
    }
}

extern "C" void kernel_launch(void* const* d_in, const int* in_sizes, int n_in,
                              void* d_out, int out_size, void* d_ws, size_t ws_size,
                              hipStream_t stream) {
    const float* z_c = (const float*)d_in[0];
    const float* z_d = (const float*)d_in[1];
    const float* W1  = (const float*)d_in[2];
    const float* b1  = (const float*)d_in[3];
    const float* W2  = (const float*)d_in[4];
    const float* b2  = (const float*)d_in[5];
    const float* Wo  = (const float*)d_in[6];
    // d_in[7] = bo: shifts T0.mean and every LSE equally -> cancels; omitted.
    float* out   = (float*)d_out;

    float* Apf   = (float*)d_ws;                 // 65536 fp32, frag-order
    float* Bp    = Apf + NN * 64;                // 65536 fp32, row-major
    uint4* W2hi  = (uint4*)(Bp + NN * 64);       // 512 uint4 (8 KB)
    uint4* W2lo  = W2hi + 512;                   // 512 uint4 (8 KB)
    float* Srow  = (float*)(W2lo + 512);         // 1024 fp32
    float* T0row = Srow + NN;                    // 1024 fp32

    prep_kernel<<<514, 256, 0, stream>>>(z_c, z_d, W1, b1, W2, Apf, Bp, W2hi, W2lo, Srow);
    main_kernel<<<4096, 256, 0, stream>>>(Apf, Bp, W2hi, W2lo, b2, Wo, Srow, T0row);
    combine_finish<<<1, 1024, 0, stream>>>(Srow, T0row, out);
}

// Round 9
// 99.671 us; speedup vs baseline: 2.3944x; 2.3944x over previous
//
#include <hip/hip_runtime.h>
#include <hip/hip_fp16.h>
#include <math.h>

#define NN 1024

typedef _Float16 half8 __attribute__((ext_vector_type(8)));
typedef float f32x4 __attribute__((ext_vector_type(4)));

union H8U { uint4 u; half8 h; };

__device__ __forceinline__ unsigned short h_bits(float x) {
    _Float16 h = (_Float16)x;          // RNE
    unsigned short b;
    __builtin_memcpy(&b, &h, 2);
    return b;
}

// ---- prep: blocks [0,512): A' = z_c@W1c + b1 -> fp16 frag-order Aph;
//            B = z_d@W1d -> fp16 frag-order Bph (per-i, per-q 16-half slices).
//            blocks [512,514): W2 -> fp16 MFMA frag layout W2h, zero Srow.
__global__ void prep_kernel(const float* __restrict__ z_c, const float* __restrict__ z_d,
                            const float* __restrict__ W1, const float* __restrict__ b1,
                            const float* __restrict__ W2,
                            unsigned short* __restrict__ Aph,
                            unsigned short* __restrict__ Bph,
                            uint4* __restrict__ W2h,
                            float* __restrict__ Srow) {
    if (blockIdx.x < 512) {
        int t = blockIdx.x * 256 + threadIdx.x;
        int sel = t >> 16;            // 0 -> A', 1 -> B
        int idx = t & 0xffff;
        int n = idx >> 6, h = idx & 63;
        const float* z = (sel ? z_d : z_c) + n * 64;
        const float* w = W1 + (sel ? 4096 : 0) + h;   // W1 (128,64) row-major
        float a0 = sel ? 0.f : b1[h], a1 = 0.f;
        #pragma unroll
        for (int k = 0; k < 64; k += 2) {
            a0 = fmaf(z[k],     w[k * 64],       a0);
            a1 = fmaf(z[k + 1], w[(k + 1) * 64], a1);
        }
        unsigned short val = h_bits(a0 + a1);   // fp32-exact matmul, one RNE to fp16
        int s = h >> 5, q = (h >> 3) & 3, e = h & 7;
        if (sel) {
            // Bph[i][q][slot]: slot = s*8+e ; lane q-group reads contiguous 16 halves
            Bph[n * 64 + q * 16 + s * 8 + e] = val;
        } else {
            // Aph[tile][lane][slot]: tile = n>>4, lane = q*16 + (n&15)
            Aph[(n >> 4) * 1024 + (q * 16 + (n & 15)) * 16 + s * 8 + e] = val;
        }
    } else {
        int tt = (blockIdx.x - 512) * 256 + threadIdx.x;   // 0..511
        Srow[tt] = 0.f; Srow[tt + 512] = 0.f;
        int f = tt >> 6, lane = tt & 63;                   // f = s*4 + t, 8 frags
        int s = f >> 2, t4 = f & 3, q = lane >> 4, l15 = lane & 15;
        int n = t4 * 16 + l15;
        unsigned w4[4];
        #pragma unroll
        for (int p = 0; p < 4; ++p) {
            int k = s * 32 + q * 8 + 2 * p;
            unsigned lo = h_bits(W2[k * 64 + n]);
            unsigned hi = h_bits(W2[(k + 1) * 64 + n]);
            w4[p] = lo | (hi << 16);
        }
        W2h[f * 64 + lane] = make_uint4(w4[0], w4[1], w4[2], w4[3]);
    }
}

// ---- main: block = (i, quarter). 4096 blocks x 256 thr; each wave 4 j-tiles of 16.
// FP16 single-precision pipeline (halves MFMA count, W2 bytes, A bytes, frag VALU
// vs R7's bf16 hi+lo). Operand-swapped mfma_f32_16x16x32_f16: acc[t][r] =
// h2pre[j = jb+l15][h = t*16 + q*4 + r], acc initialized to b2.
__global__ void __launch_bounds__(256, 4)
main_kernel(const unsigned short* __restrict__ Aph, const unsigned short* __restrict__ Bph,
            const uint4* __restrict__ W2h,
            const float* __restrict__ b2, const float* __restrict__ Wo,
            float* __restrict__ Srow, float* __restrict__ T0row) {
    const int i       = blockIdx.x >> 2;
    const int quarter = blockIdx.x & 3;
    const int lane = threadIdx.x & 63;
    const int wave = threadIdx.x >> 6;
    const int l15  = lane & 15;
    const int q    = lane >> 4;

    // W2 fragments: 8 coalesced dwordx4 loads (8 KB block working set, L1-hot)
    half8 W[2][4];   // [s][t]
    #pragma unroll
    for (int f = 0; f < 8; ++f) {
        H8U u; u.u = W2h[f * 64 + lane];
        W[f >> 2][f & 3] = u.h;
    }

    // B_i per-lane slice (fp16 frag order): 2 dwordx4 = 16 halves, k = s*32+q*8+e
    H8U cb0, cb1;
    {
        const uint4* bp = (const uint4*)(Bph + i * 64 + q * 16);
        cb0.u = bp[0];   // s=0 (k 0..31 slice)
        cb1.u = bp[1];   // s=1 (k 32..63 slice)
    }

    // b2 folded into acc init; Wo per-lane, element (t,r) is h = t*16 + q*4 + r
    f32x4 b2v[4];
    float wov[4][4];
    #pragma unroll
    for (int t = 0; t < 4; ++t) {
        float4 bt = *(const float4*)(b2 + t * 16 + q * 4);
        float4 wt = *(const float4*)(Wo + t * 16 + q * 4);
        b2v[t] = (f32x4){bt.x, bt.y, bt.z, bt.w};
        wov[t][0] = wt.x; wov[t][1] = wt.y; wov[t][2] = wt.z; wov[t][3] = wt.w;
    }

    const int tbase = quarter * 16 + wave * 4;
    const unsigned short* ap = Aph + tbase * 1024 + lane * 16;

    // prefetch tile 0 raw fp16 (2 dwordx4 per tile)
    H8U x0, x1;
    x0.u = ((const uint4*)ap)[0];
    x1.u = ((const uint4*)ap)[1];

    const half8 zero = {0, 0, 0, 0, 0, 0, 0, 0};
    float psum[4];
    float sacc = 0.f;

    #pragma unroll
    for (int tile = 0; tile < 4; ++tile) {
        // h1 frags: packed fp16 add + relu (v_pk_add_f16 / v_pk_max_f16)
        half8 a0 = __builtin_elementwise_max(x0.h + cb0.h, zero);   // k 0..31
        half8 a1 = __builtin_elementwise_max(x1.h + cb1.h, zero);   // k 32..63
        if (tile < 3) {                                              // prefetch next
            const uint4* nx = (const uint4*)(ap + (tile + 1) * 1024);
            x0.u = nx[0];
            x1.u = nx[1];
        }

        f32x4 acc[4];
        #pragma unroll
        for (int t = 0; t < 4; ++t) acc[t] = b2v[t];
        #pragma unroll
        for (int t = 0; t < 4; ++t) {
            acc[t] = __builtin_amdgcn_mfma_f32_16x16x32_f16(W[0][t], a0, acc[t], 0, 0, 0);
            acc[t] = __builtin_amdgcn_mfma_f32_16x16x32_f16(W[1][t], a1, acc[t], 0, 0, 0);
        }

        // T1 partial: per lane h = t*16 + q*4 + r ; 4 parallel chains
        float p0 = 0.f, p1 = 0.f, p2 = 0.f, p3 = 0.f;
        #pragma unroll
        for (int t = 0; t < 4; ++t) {
            p0 = fmaf(fmaxf(acc[t][0], 0.f), wov[t][0], p0);
            p1 = fmaf(fmaxf(acc[t][1], 0.f), wov[t][1], p1);
            p2 = fmaf(fmaxf(acc[t][2], 0.f), wov[t][2], p2);
            p3 = fmaf(fmaxf(acc[t][3], 0.f), wov[t][3], p3);
        }
        psum[tile] = (p0 + p1) + (p2 + p3);
    }

    // Epilogue: 4 independent reduce/exp chains
    #pragma unroll
    for (int tile = 0; tile < 4; ++tile) {
        float ps = psum[tile];
        ps += __shfl_xor(ps, 16);
        ps += __shfl_xor(ps, 32);   // T1[j], replicated over the 4 q-groups
        const int j = (tbase + tile) * 16 + l15;
        if (j == i && q == 0) T0row[i] = ps;   // diagonal: exactly one writer
        sacc += __expf(ps);
    }
    // reduce over l15 only (q-groups are exact replicas -> exact sum)
    sacc += __shfl_xor(sacc, 1);
    sacc += __shfl_xor(sacc, 2);
    sacc += __shfl_xor(sacc, 4);
    sacc += __shfl_xor(sacc, 8);
    if (lane == 0) atomicAdd(&Srow[i], sacc);   // 16 adds per i, 1024 addresses
}

// ---- combine+finish: 1 block x 1024 thr. bound = mean(T0) - (mean(log Srow) - ln N)
__global__ void __launch_bounds__(1024)
combine_finish(const float* __restrict__ Srow, const float* __restrict__ T0row,
               float* __restrict__ out) {
    int i = threadIdx.x;
    float l  = logf(Srow[i]);
    float t0 = T0row[i];
    #pragma unroll
    for (int off = 1; off < 64; off <<= 1) {
        l  += __shfl_xor(l, off);
        t0 += __shfl_xor(t0, off);
    }
    __shared__ float sl[16], st[16];
    int w = threadIdx.x >> 6;
    if ((threadIdx.x & 63) == 0) { sl[w] = l; st[w] = t0; }
    __syncthreads();
    if (threadIdx.x == 0) {
        float L = 0.f, T = 0.f;
        #pragma unroll
        for (int k = 0; k < 16; ++k) { L += sl[k]; T += st[k]; }
        out[0] = (T - L) * (1.0f / 1024.0f) + 6.9314718055994531f;
    }
}

extern "C" void kernel_launch(void* const* d_in, const int* in_sizes, int n_in,
                              void* d_out, int out_size, void* d_ws, size_t ws_size,
                              hipStream_t stream) {
    const float* z_c = (const float*)d_in[0];
    const float* z_d = (const float*)d_in[1];
    const float* W1  = (const float*)d_in[2];
    const float* b1  = (const float*)d_in[3];
    const float* W2  = (const float*)d_in[4];
    const float* b2  = (const float*)d_in[5];
    const float* Wo  = (const float*)d_in[6];
    // d_in[7] = bo: shifts T0.mean and every LSE equally -> cancels; omitted.
    float* out   = (float*)d_out;

    unsigned short* Aph = (unsigned short*)d_ws;   // 65536 fp16 (128 KB), frag-order
    unsigned short* Bph = Aph + NN * 64;           // 65536 fp16 (128 KB), frag-order
    uint4* W2h  = (uint4*)(Bph + NN * 64);         // 512 uint4 (8 KB)
    float* Srow = (float*)(W2h + 512);             // 1024 fp32
    float* T0row = Srow + NN;                      // 1024 fp32

    prep_kernel<<<514, 256, 0, stream>>>(z_c, z_d, W1, b1, W2, Aph, Bph, W2h, Srow);
    main_kernel<<<4096, 256, 0, stream>>>(Aph, Bph, W2h, b2, Wo, Srow, T0row);
    combine_finish<<<1, 1024, 0, stream>>>(Srow, T0row, out);
}